// Round 9
// baseline (186.950 us; speedup 1.0000x reference)
//
#include <hip/hip_runtime.h>
#include <math.h>

#define D_INNER 5120
#define DT_RANK 160
#define N_STATE 16
#define BATCH   256
#define KTOT    192               // 160 (dt_low) | 16 (B) | 16 (C)

// ---- K1 config: 256-thr blocks, 4 waves x 40-dd chunks, intra-block reduce ----
#define BGRP    8                 // batches per block
#define NBG     (BATCH / BGRP)    // 32
#define DDBLK   160               // dd per block (4 waves x 40)
#define NDDB    (D_INNER / DDBLK) // 32 -> SPLIT partials
#define SPLIT   32

// ---- K3 config: 4 lanes per (b,d) item; 64 d/block, 4 batches/block ----
#define K3_BT   4
#define K3_DD   64                // d-values per block (256 thr / 4 lanes)

// ---- workspace layout (float offsets) ----
#define OFF_T     0
#define SZ_T      (BATCH * KTOT)                  // 49,152
#define OFF_P     (OFF_T + SZ_T)
#define SZ_P      (SPLIT * BATCH * KTOT)          // 1,572,864 (6.3 MB)
#define OFF_SBC   (OFF_P + SZ_P)                  // sbc[b] = sum_n T[b][160+n]*T[b][176+n]

// ---------------------------------------------------------------------------
// K1: projection GEMM partials (unchanged, ~10 us).
// ---------------------------------------------------------------------------
__global__ __launch_bounds__(256) void k1_gemm(const float* __restrict__ x,
                                               const float* __restrict__ Wdtlow,
                                               const float* __restrict__ WB,
                                               const float* __restrict__ WC,
                                               float* __restrict__ ws) {
    __shared__ float lds[4 * BGRP * KTOT];   // 6144 floats = 24 KB
    const int tid  = threadIdx.x;
    const int lane = tid & 63;
    const int wv   = tid >> 6;               // wave 0..3
    const int b0   = blockIdx.x * BGRP;
    const int ddB  = blockIdx.y * DDBLK;

    float* xs = lds;
    for (int j = tid; j < (BGRP * DDBLK) / 4; j += 256) {   // 320 float4
        int i  = j / (DDBLK / 4);
        int c4 = j % (DDBLK / 4);
        float4 v = *(const float4*)(x + (size_t)(b0 + i) * D_INNER + ddB + c4 * 4);
        *(float4*)(xs + i * DDBLK + c4 * 4) = v;
    }
    __syncthreads();

    const int dd0 = wv * 40;
    const float* p0 = Wdtlow + (size_t)(ddB + dd0) * DT_RANK + lane;
    const float* p1 = p0 + 64;
    const float* p2;
    int st2;
    if (lane < 32)      { p2 = p0 + 128;                                          st2 = DT_RANK; }
    else if (lane < 48) { p2 = WB + (size_t)(ddB + dd0) * N_STATE + (lane - 32);  st2 = N_STATE; }
    else                { p2 = WC + (size_t)(ddB + dd0) * N_STATE + (lane - 48);  st2 = N_STATE; }

    float acc0[BGRP], acc1[BGRP], acc2[BGRP];
#pragma unroll
    for (int i = 0; i < BGRP; ++i) { acc0[i] = 0.f; acc1[i] = 0.f; acc2[i] = 0.f; }

#pragma unroll 2
    for (int g = 0; g < 10; ++g) {           // 4 dd per group
        float w0[4], w1[4], w2[4];
#pragma unroll
        for (int u = 0; u < 4; ++u) {
            int dd = g * 4 + u;
            w0[u] = p0[(size_t)dd * DT_RANK];
            w1[u] = p1[(size_t)dd * DT_RANK];
            w2[u] = p2[(size_t)dd * st2];
        }
#pragma unroll
        for (int i = 0; i < BGRP; ++i) {
            float4 xv = *(const float4*)(xs + i * DDBLK + dd0 + g * 4);
            acc0[i] += xv.x * w0[0] + xv.y * w0[1] + xv.z * w0[2] + xv.w * w0[3];
            acc1[i] += xv.x * w1[0] + xv.y * w1[1] + xv.z * w1[2] + xv.w * w1[3];
            acc2[i] += xv.x * w2[0] + xv.y * w2[1] + xv.z * w2[2] + xv.w * w2[3];
        }
    }
    __syncthreads();

#pragma unroll
    for (int i = 0; i < BGRP; ++i) {
        float* r = lds + wv * (BGRP * KTOT) + i * KTOT;
        r[lane]       = acc0[i];
        r[lane + 64]  = acc1[i];
        r[lane + 128] = acc2[i];
    }
    __syncthreads();

    float* P = ws + OFF_P + (size_t)blockIdx.y * (BATCH * KTOT) + (size_t)b0 * KTOT;
#pragma unroll
    for (int r = 0; r < 6; ++r) {
        int idx = tid + r * 256;
        P[idx] = lds[idx] + lds[idx + 1536] + lds[idx + 3072] + lds[idx + 4608];
    }
}

// ---------------------------------------------------------------------------
// K2: reduce split-K partials -> T[256][192], plus hoisted sbc[b]. (unchanged)
// ---------------------------------------------------------------------------
__global__ __launch_bounds__(192) void k2_reduce(float* __restrict__ ws) {
    __shared__ float ts[KTOT];
    const int b   = blockIdx.x;
    const int col = threadIdx.x;
    const float* P = ws + OFF_P + (size_t)b * KTOT + col;
    float a = 0.f;
#pragma unroll
    for (int s = 0; s < SPLIT; ++s) a += P[(size_t)s * (BATCH * KTOT)];
    ws[OFF_T + b * KTOT + col] = a;
    ts[col] = a;
    __syncthreads();
    if (col == 0) {
        float s2 = 0.f;
#pragma unroll
        for (int n = 0; n < N_STATE; ++n) s2 += ts[160 + n] * ts[176 + n];
        ws[OFF_SBC + b] = s2;
    }
}

// ---------------------------------------------------------------------------
// K3: COOPERATIVE-LANE round — 4 lanes per (b,d) item.
// Diagnosis (r4/r6/r8): scan is the dominant cost and is occupancy-
// insensitive. Cause: thread-owns-item mapping reads h0 as 4x float4 at
// 64B LANE STRIDE -> every wave instruction touches 64 cache lines (vs 16
// coalesced) -> 4x line-request amplification (~5.2M requests), a per-CU
// TA/tag THROUGHPUT wall that no amount of waves or prefetch depth fixes.
// Fix: remap work. thread = (d = tid/4, n-slice = tid%4):
//  * h0 load per batch at base + tid*16B -> PERFECTLY coalesced (16 lines).
//  * A load identical pattern -> coalesced.
//  * GEMM split-k: lane sums k in [ng*40, ng*40+40) -> 160 FMA/thread
//    (was 640); partials tree-reduced with 2 shfl_xor (commutative pairs,
//    deterministic ((p0+p1)+(p2+p3))).
//  * y: per-lane 4-term chain (same order as old y0..y3 partials), then
//    2 shfl_xor -> EXACTLY the old ((y0+y1)+(y2+y3)) tree.
//  * T rows staged once in LDS (3KB): b128 reads land on disjoint bank
//    quads per n-slice, broadcast across the 16 lanes sharing a slice.
// Grid (80,64)=5120 blocks, 256 thr; ~70 VGPR -> (256,6); LDS 3KB.
// ---------------------------------------------------------------------------
__global__ __launch_bounds__(256, 6) void k3_fused(const float* __restrict__ Wdt,
                                                   const float* __restrict__ b_dt,
                                                   const float* __restrict__ x,
                                                   const float* __restrict__ A,
                                                   const float* __restrict__ Dv,
                                                   const float* __restrict__ h0,
                                                   const float* __restrict__ ws,
                                                   float* __restrict__ out) {
    __shared__ __align__(16) float Tl[K3_BT * KTOT];   // 768 floats = 3 KB
    const int tid  = threadIdx.x;
    const int did  = tid >> 2;                 // 0..63  (d within block)
    const int ng   = tid & 3;                  // n-slice / k-slice index
    const int dblk = blockIdx.x * K3_DD;
    const int d    = dblk + did;
    const int b0   = blockIdx.y * K3_BT;
    const float* SB = ws + OFF_SBC;

    // ---- stage T rows b0..b0+3 (coalesced: 3 floats/thread) ----
    {
        const float* Tg = ws + OFF_T + (size_t)b0 * KTOT;
#pragma unroll
        for (int j = tid; j < K3_BT * KTOT; j += 256) Tl[j] = Tg[j];
    }

    // ---- coalesced streaming loads (all at base + tid*16B patterns) ----
    float4 h[K3_BT];
#pragma unroll
    for (int bi = 0; bi < K3_BT; ++bi)
        h[bi] = *(const float4*)(h0 + ((size_t)(b0 + bi) * D_INNER + dblk) * N_STATE
                                 + tid * 4);
    float4 av = *(const float4*)(A + (size_t)dblk * N_STATE + tid * 4);

    float xv[K3_BT];
#pragma unroll
    for (int bi = 0; bi < K3_BT; ++bi) xv[bi] = x[(size_t)(b0 + bi) * D_INNER + d];

    const float bdt = b_dt[d];
    const float Dd  = Dv[d];

    __syncthreads();                           // T staged

    // ---- delta GEMM, split-k: lane ng sums k in [ng*40, ng*40+40) ----
    // Wdt loads: per instr 4 k-rows x 16 consecutive dwords -> ~4-8 lines.
    float acc[K3_BT] = {0.f, 0.f, 0.f, 0.f};
    {
        const float* wp = Wdt + (size_t)(ng * 40) * D_INNER + d;
        const int kb = ng * 40;
#pragma unroll 2
        for (int q = 0; q < 10; ++q) {
            float w0 = wp[(size_t)(q * 4 + 0) * D_INNER];
            float w1 = wp[(size_t)(q * 4 + 1) * D_INNER];
            float w2 = wp[(size_t)(q * 4 + 2) * D_INNER];
            float w3 = wp[(size_t)(q * 4 + 3) * D_INNER];
#pragma unroll
            for (int bi = 0; bi < K3_BT; ++bi) {
                float4 t = *(const float4*)&Tl[bi * KTOT + kb + q * 4];
                acc[bi] += t.x * w0;
                acc[bi] += t.y * w1;
                acc[bi] += t.z * w2;
                acc[bi] += t.w * w3;
            }
        }
    }
    // reduce split-k partials across the 4-lane group (deterministic tree)
#pragma unroll
    for (int bi = 0; bi < K3_BT; ++bi) {
        acc[bi] += __shfl_xor(acc[bi], 1);
        acc[bi] += __shfl_xor(acc[bi], 2);
    }

    // ---- scan: per batch, each lane handles its 4 n's, tree-reduce y ----
#pragma unroll
    for (int bi = 0; bi < K3_BT; ++bi) {
        const int b = b0 + bi;
        float v     = acc[bi] + bdt;
        float delta = (v > 20.f) ? v : log1pf(__expf(v));
        float sbc   = SB[b];                          // uniform -> s_load

        const float* Cb = &Tl[bi * KTOT + 176 + ng * 4];  // disjoint banks
        float y;
        y  = __expf(delta * av.x) * h[bi].x * Cb[0];
        y += __expf(delta * av.y) * h[bi].y * Cb[1];
        y += __expf(delta * av.z) * h[bi].z * Cb[2];
        y += __expf(delta * av.w) * h[bi].w * Cb[3];
        y += __shfl_xor(y, 1);
        y += __shfl_xor(y, 2);                        // ((y0+y1)+(y2+y3))

        if (ng == bi)
            out[(size_t)b * D_INNER + d] = xv[bi] * (Dd + delta * sbc) + y;
    }
}

// ---------------------------------------------------------------------------
extern "C" void kernel_launch(void* const* d_in, const int* in_sizes, int n_in,
                              void* d_out, int out_size, void* d_ws, size_t ws_size,
                              hipStream_t stream) {
    const float* x      = (const float*)d_in[0];
    const float* Wdtlow = (const float*)d_in[1];
    const float* Wdt    = (const float*)d_in[2];
    const float* bdt    = (const float*)d_in[3];
    const float* WB     = (const float*)d_in[4];
    const float* WC     = (const float*)d_in[5];
    const float* A      = (const float*)d_in[6];
    const float* Dv     = (const float*)d_in[7];
    const float* h0     = (const float*)d_in[8];
    float* ws  = (float*)d_ws;
    float* out = (float*)d_out;

    // K1: projection GEMM partials (1024 blocks, unchanged)
    hipLaunchKernelGGL(k1_gemm, dim3(NBG, NDDB), dim3(256), 0, stream,
                       x, Wdtlow, WB, WC, ws);
    // K2: reduce partials -> T[256][192] + sbc[256]
    hipLaunchKernelGGL(k2_reduce, dim3(BATCH), dim3(192), 0, stream, ws);
    // K3: cooperative-lane fused GEMM+scan, grid (80,64)=5120 blocks
    hipLaunchKernelGGL(k3_fused, dim3(D_INNER / K3_DD, BATCH / K3_BT), dim3(256),
                       0, stream, Wdt, bdt, x, A, Dv, h0, ws, out);
}